// Round 3
// baseline (991.040 us; speedup 1.0000x reference)
//
#include <hip/hip_runtime.h>
#include <hip/hip_bf16.h>

typedef __hip_bfloat16 bf16;

#define Bc 2
#define Nc 512
#define Rc 64
#define Tc 128
#define Ec 64
#define Hc 8
#define THc 1024
#define FFc 256

__device__ __forceinline__ bf16  f2b(float x){ return __float2bfloat16(x); }
__device__ __forceinline__ float us2f(unsigned short u){
  union { unsigned int i; float f; } c; c.i = ((unsigned int)u) << 16; return c.f;
}
__device__ __forceinline__ float clip5(float x){ return fminf(fmaxf(x, -5.0f), 5.0f); }

__device__ __forceinline__ float wave_sum64(float v){
#pragma unroll
  for (int o = 32; o > 0; o >>= 1) v += __shfl_xor(v, o, 64);
  return v;
}
// two interleaved wave sums (ILP across the serial shuffle chain)
__device__ __forceinline__ void wave_sum64x2(float& a, float& b){
#pragma unroll
  for (int o = 32; o > 0; o >>= 1){
    a += __shfl_xor(a, o, 64);
    b += __shfl_xor(b, o, 64);
  }
}

// sum across the 16 lanes that co-own one row (lanes are 16-aligned groups)
__device__ __forceinline__ float rowred16_sum(float v){
  v += __shfl_xor(v, 1, 64);
  v += __shfl_xor(v, 2, 64);
  v += __shfl_xor(v, 4, 64);
  v += __shfl_xor(v, 8, 64);
  return v;
}

// ---------------- prep: ds = D_S@W_emb + b_emb ; qhat_sr = I_param(head)@Wq_sr ----
__global__ __launch_bounds__(64) void k_prep(
    const float* __restrict__ DS, const float* __restrict__ Wemb,
    const float* __restrict__ bemb, const float* __restrict__ Ip,
    const float* __restrict__ Wq, float* __restrict__ ds, float* __restrict__ qhat)
{
  int bid = blockIdx.x, t = threadIdx.x;
  if (bid < Nc){
    int n = bid, e = t;
    __shared__ float row[Rc];
    row[t] = DS[n*Rc + t];
    __syncthreads();
    float acc = bemb[e];
    for (int r = 0; r < Rc; ++r) acc += row[r] * Wemb[r*Ec + e];
    ds[n*Ec + e] = acc;
  } else {
    int r = bid - Nc;
    __shared__ float irow[Ec];
    irow[t] = Ip[r*Ec + t];
    __syncthreads();
    int h = t >> 3, d = t & 7;
    float acc = 0.0f;
#pragma unroll
    for (int d0 = 0; d0 < 8; ++d0) acc += irow[h*8 + d0] * Wq[d0*8 + d];
    qhat[r*Ec + h*8 + d] = acc;   // [R][H][D]
  }
}

// ---------------- khat_sr = (key+ds)@Wk per head; vhat_sr = value@Wv --------------
__global__ __launch_bounds__(256) void k_proj_sr(
    const float* __restrict__ key, const float* __restrict__ value,
    const float* __restrict__ ds, const float* __restrict__ Wk,
    const float* __restrict__ Wv, float* __restrict__ khat, float* __restrict__ vhat)
{
  __shared__ float wk[64], wv[64];
  int t = threadIdx.x;
  if (t < 64){ wk[t] = Wk[t]; wv[t] = Wv[t]; }
  __syncthreads();
  int u = blockIdx.x*256 + t;              // (b,n,t,h) unit, < 1048576
  int h = u & 7;
  int nt = u >> 3;                         // (b*N+n)*T + t
  int n = (nt / Tc) % Nc;
  const float* kp = key + (size_t)u*8;
  const float* vp = value + (size_t)u*8;
  const float* dsp = ds + n*Ec + h*8;
  float kin[8], vin[8];
#pragma unroll
  for (int d = 0; d < 8; ++d){ kin[d] = kp[d] + dsp[d]; vin[d] = vp[d]; }
  float* ko = khat + (size_t)u*8;
  float* vo = vhat + (size_t)u*8;
#pragma unroll
  for (int d = 0; d < 8; ++d){
    float ka = 0.0f, va = 0.0f;
#pragma unroll
    for (int d0 = 0; d0 < 8; ++d0){ ka += kin[d0]*wk[d0*8+d]; va += vin[d0]*wv[d0*8+d]; }
    ko[d] = ka; vo[d] = va;
  }
}

// ---------------- sr attention v3: all 8 heads in-thread, direct fp32 att write --
// block = (b,t,nh): 4 waves, wave w covers n in [nh*128 + w*32, +32). lane = r.
// Thread holds q-row (64) + PV acc (64); att[r][n][8h] written as 32B directly.
// PV partials: in-block cross-wave LDS reduce -> pre_part[nh] (4 buffers).
__global__ __launch_bounds__(256) void k_attn_sr(
    const float* __restrict__ khat, const float* __restrict__ vhat,
    const float* __restrict__ qhat, const int* __restrict__ adj_sr,
    float* __restrict__ o_asr, float* __restrict__ pre_part)
{
  __shared__ float red[2][4][64][4];
  int bid = blockIdx.x;
  int nh = bid & 3; int bt = bid >> 2;
  int t = bt & (Tc - 1); int b = bt >> 7;
  int tid = threadIdx.x;
  int r = tid & 63, w = tid >> 6;
  float q[64];
#pragma unroll
  for (int i = 0; i < 16; ++i)
    *(float4*)&q[i*4] = *(const float4*)&qhat[r*64 + i*4];
  float acc[64];
#pragma unroll
  for (int i = 0; i < 64; ++i) acc[i] = 0.0f;
  int n0 = nh*128 + w*32;
  for (int n = n0; n < n0 + 32; ++n){
    size_t ko = ((size_t)((b*Nc + n)*Tc + t))*Ec;
    const float* kp = khat + ko;
    const float* vp = vhat + ko;
    int mflag = adj_sr[n*Rc + r];
    float p[8], s[8];
#pragma unroll
    for (int h = 0; h < 8; ++h){
      float4 ka = *(const float4*)&kp[h*8];
      float4 kb = *(const float4*)&kp[h*8 + 4];
      float e = q[h*8+0]*ka.x + q[h*8+1]*ka.y + q[h*8+2]*ka.z + q[h*8+3]*ka.w
              + q[h*8+4]*kb.x + q[h*8+5]*kb.y + q[h*8+6]*kb.z + q[h*8+7]*kb.w;
      e = mflag ? clip5(e*0.125f) : -5.0f;
      p[h] = __expf(e);
      s[h] = p[h];
    }
#pragma unroll
    for (int o = 32; o > 0; o >>= 1){
#pragma unroll
      for (int h = 0; h < 8; ++h) s[h] += __shfl_xor(s[h], o, 64);
    }
    float a[8];
#pragma unroll
    for (int h = 0; h < 8; ++h) a[h] = p[h] * __builtin_amdgcn_rcpf(s[h]);
    size_t ao = ((size_t)((b*Rc + r)*Nc + n))*THc + t*8;   // [B][R][N][TH]
    *(float4*)&o_asr[ao]     = make_float4(a[0], a[1], a[2], a[3]);
    *(float4*)&o_asr[ao + 4] = make_float4(a[4], a[5], a[6], a[7]);
#pragma unroll
    for (int h = 0; h < 8; ++h){
      float4 va = *(const float4*)&vp[h*8];
      float4 vb = *(const float4*)&vp[h*8 + 4];
      float ah = a[h];
      acc[h*8+0] += ah*va.x; acc[h*8+1] += ah*va.y;
      acc[h*8+2] += ah*va.z; acc[h*8+3] += ah*va.w;
      acc[h*8+4] += ah*vb.x; acc[h*8+5] += ah*vb.y;
      acc[h*8+6] += ah*vb.z; acc[h*8+7] += ah*vb.w;
    }
  }
  // cross-wave PV reduce: 16 chunks of 4 floats, parity double-buffered
#pragma unroll
  for (int c = 0; c < 16; ++c){
    int par = c & 1;
    *(float4*)&red[par][w][r][0] =
        make_float4(acc[c*4+0], acc[c*4+1], acc[c*4+2], acc[c*4+3]);
    __syncthreads();
    if (w == 0){
      float4 s0 = *(const float4*)&red[par][0][r][0];
      float4 s1 = *(const float4*)&red[par][1][r][0];
      float4 s2 = *(const float4*)&red[par][2][r][0];
      float4 s3 = *(const float4*)&red[par][3][r][0];
      size_t po = (size_t)nh*1048576 +
                  ((size_t)((b*Rc + r)*Tc + t))*Ec + c*4;   // [nh][B][R][T][E]
      *(float4*)&pre_part[po] = make_float4(s0.x+s1.x+s2.x+s3.x,
                                            s0.y+s1.y+s2.y+s3.y,
                                            s0.z+s1.z+s2.z+s3.z,
                                            s0.w+s1.w+s2.w+s3.w);
    }
  }
}

// ---------------- rr attention v3: all 8 heads in-thread, direct fp32 att write --
// block = (b,t): 4 waves, wave w covers k in [w*16, +16). lane = q.
__global__ __launch_bounds__(256) void k_attn_rr(
    const float* __restrict__ qh, const float* __restrict__ kh,
    const float* __restrict__ vh, const int* __restrict__ adj_r,
    float* __restrict__ o_arr, float* __restrict__ pre)
{
  __shared__ float red[2][4][64][4];
  int bid = blockIdx.x;
  int t = bid & (Tc - 1); int b = bid >> 7;
  int tid = threadIdx.x;
  int qq = tid & 63, w = tid >> 6;
  size_t row = (size_t)(b*Rc + qq)*Tc + t;
  float q[64];
#pragma unroll
  for (int i = 0; i < 16; ++i)
    *(float4*)&q[i*4] = *(const float4*)&qh[row*64 + i*4];
  float acc[64];
#pragma unroll
  for (int i = 0; i < 64; ++i) acc[i] = 0.0f;
  int k0 = w*16;
  for (int k = k0; k < k0 + 16; ++k){
    size_t ko = ((size_t)((b*Rc + k)*Tc + t))*Ec;
    const float* kp = kh + ko;
    const float* vp = vh + ko;
    int mflag = adj_r[qq*Rc + k];
    float p[8], s[8];
#pragma unroll
    for (int h = 0; h < 8; ++h){
      float4 ka = *(const float4*)&kp[h*8];
      float4 kb = *(const float4*)&kp[h*8 + 4];
      float e = q[h*8+0]*ka.x + q[h*8+1]*ka.y + q[h*8+2]*ka.z + q[h*8+3]*ka.w
              + q[h*8+4]*kb.x + q[h*8+5]*kb.y + q[h*8+6]*kb.z + q[h*8+7]*kb.w;
      e = mflag ? clip5(e*0.125f) : -5.0f;
      p[h] = __expf(e);
      s[h] = p[h];
    }
#pragma unroll
    for (int o = 32; o > 0; o >>= 1){
#pragma unroll
      for (int h = 0; h < 8; ++h) s[h] += __shfl_xor(s[h], o, 64);
    }
    float a[8];
#pragma unroll
    for (int h = 0; h < 8; ++h) a[h] = p[h] * __builtin_amdgcn_rcpf(s[h]);
    size_t ao = ((size_t)((b*Rc + qq)*Rc + k))*THc + t*8;  // [B][Q][K][TH]
    *(float4*)&o_arr[ao]     = make_float4(a[0], a[1], a[2], a[3]);
    *(float4*)&o_arr[ao + 4] = make_float4(a[4], a[5], a[6], a[7]);
#pragma unroll
    for (int h = 0; h < 8; ++h){
      float4 va = *(const float4*)&vp[h*8];
      float4 vb = *(const float4*)&vp[h*8 + 4];
      float ah = a[h];
      acc[h*8+0] += ah*va.x; acc[h*8+1] += ah*va.y;
      acc[h*8+2] += ah*va.z; acc[h*8+3] += ah*va.w;
      acc[h*8+4] += ah*vb.x; acc[h*8+5] += ah*vb.y;
      acc[h*8+6] += ah*vb.z; acc[h*8+7] += ah*vb.w;
    }
  }
#pragma unroll
  for (int c = 0; c < 16; ++c){
    int par = c & 1;
    *(float4*)&red[par][w][qq][0] =
        make_float4(acc[c*4+0], acc[c*4+1], acc[c*4+2], acc[c*4+3]);
    __syncthreads();
    if (w == 0){
      float4 s0 = *(const float4*)&red[par][0][qq][0];
      float4 s1 = *(const float4*)&red[par][1][qq][0];
      float4 s2 = *(const float4*)&red[par][2][qq][0];
      float4 s3 = *(const float4*)&red[par][3][qq][0];
      *(float4*)&pre[row*64 + c*4] = make_float4(s0.x+s1.x+s2.x+s3.x,
                                                 s0.y+s1.y+s2.y+s3.y,
                                                 s0.z+s1.z+s2.z+s3.z,
                                                 s0.w+s1.w+s2.w+s3.w);
    }
  }
}

// ---------------- rs attention: block=(b,t,h) x 512 thr, thread=q ---------------
__global__ __launch_bounds__(512) void k_attn_rs(
    const float* __restrict__ query, const float* __restrict__ ds,
    const float* __restrict__ Wq, const float* __restrict__ kh,
    const float* __restrict__ vh, bf16* __restrict__ att_c, float* __restrict__ pre)
{
  __shared__ float wq[64];
  __shared__ float kl[64][8];
  __shared__ float vl[64][8];
  __shared__ float redS[2][2][8];
  int bid = blockIdx.x;
  int b = bid >> 10, th = bid & 1023;
  int t = th >> 3, h = th & 7;
  int q = threadIdx.x;
  if (q < 64) wq[q] = Wq[q];
  {
    int kk = q >> 3, d = q & 7;
    size_t o = ((size_t)((b*Rc + kk)*Tc + t))*Ec + h*8 + d;
    kl[kk][d] = kh[o];
    vl[kk][d] = vh[o];
  }
  __syncthreads();
  size_t qro = ((size_t)((b*Nc + q)*Tc + t))*Ec + h*8;
  const float* dsp = ds + q*Ec + h*8;
  float xin[8], qv[8];
#pragma unroll
  for (int d = 0; d < 8; ++d) xin[d] = query[qro + d] + dsp[d];
#pragma unroll
  for (int d = 0; d < 8; ++d){
    float a = 0.0f;
#pragma unroll
    for (int d0 = 0; d0 < 8; ++d0) a += xin[d0]*wq[d0*8 + d];
    qv[d] = a;
  }
  float acc[8] = {0,0,0,0,0,0,0,0};
  int lane = q & 63, wv = q >> 6;
  for (int k = 0; k < 64; k += 2){
    float eA = 0.0f, eB = 0.0f;
#pragma unroll
    for (int d = 0; d < 8; ++d){ eA += qv[d]*kl[k][d]; eB += qv[d]*kl[k+1][d]; }
    eA = clip5(eA*0.125f);
    eB = clip5(eB*0.125f);
    float pA = __expf(eA), pB = __expf(eB);
    float sA = pA, sB = pB;
    wave_sum64x2(sA, sB);
    int pb = (k >> 1) & 1;
    if (lane == 0){ redS[pb][0][wv] = sA; redS[pb][1][wv] = sB; }
    __syncthreads();
    float stA = 0.0f, stB = 0.0f;
#pragma unroll
    for (int i = 0; i < 8; ++i){ stA += redS[pb][0][i]; stB += redS[pb][1][i]; }
    float aA = pA/stA, aB = pB/stB;
    size_t ao = ((size_t)(b*Rc + k)*THc + th)*Nc + q;
    att_c[ao] = f2b(aA);                              // [B][K][TH][Q=512]
    att_c[ao + (size_t)THc*Nc] = f2b(aB);
#pragma unroll
    for (int d = 0; d < 8; ++d) acc[d] += aA*vl[k][d] + aB*vl[k+1][d];
  }
#pragma unroll
  for (int d = 0; d < 8; ++d) pre[qro + d] = acc[d];         // [B][N][T][E]
}

// ---- transpose+widen: src bf16 [B][W][TH][C] -> dst fp32 [((b*C+c)*W+w)*TH+th] --
__global__ __launch_bounds__(256) void k_transpose(
    const unsigned short* __restrict__ src, float* __restrict__ dst,
    int W, int C)
{
  __shared__ unsigned short tile[64][66];
  int bid = blockIdx.x;
  int nct = C >> 6;
  int ct = bid % nct; bid /= nct;
  int tht = bid & 15; bid >>= 4;
  int w = bid % W; int b = bid / W;
  int tt = threadIdx.x;
  {
    int cs = tt & 63, i0 = tt >> 6;
    const unsigned short* sb = src + ((size_t)(b*W + w)*THc + tht*64)*C + ct*64;
#pragma unroll
    for (int p = 0; p < 16; ++p){
      int i = i0 + p*4;
      tile[i][cs] = sb[(size_t)i*C + cs];
    }
  }
  __syncthreads();
  {
    int i = tt & 63, c0 = tt >> 6;
#pragma unroll
    for (int p = 0; p < 16; ++p){
      int cs = c0 + p*4;
      int c = ct*64 + cs;
      dst[((size_t)(b*C + c)*W + w)*THc + tht*64 + i] = us2f(tile[i][cs]);
    }
  }
}

// -------- Wo projection: wave per row, (sum of nparts partials) @ Wo + bo -------
__global__ __launch_bounds__(256) void k_wo(
    const float* __restrict__ pre, int nparts, int pstride,
    const float* __restrict__ Wo,
    const float* __restrict__ bo, float* __restrict__ outf,
    float* __restrict__ outf2, int nrows)
{
  int gt = blockIdx.x*256 + threadIdx.x;
  int row = gt >> 6, lane = gt & 63;
  if (row >= nrows) return;
  float xin = 0.0f;
  for (int p2 = 0; p2 < nparts; ++p2)
    xin += pre[(size_t)p2*pstride + (size_t)row*64 + lane];
  float acc = bo[lane];
  for (int e = 0; e < 64; ++e){
    float xe = __shfl(xin, e, 64);
    acc += xe * Wo[e*64 + lane];
  }
  outf[(size_t)row*64 + lane] = acc;
  if (outf2) outf2[(size_t)row*64 + lane] = acc;
}

// ---------------- per-head triple projection from [rows][64] fp32 ---------------
__global__ __launch_bounds__(256) void k_proj3(
    const float* __restrict__ src, const float* Wq, const float* Wk, const float* Wv,
    float* qh, float* kh, float* vh, int nunits)
{
  __shared__ float wq[64], wk[64], wv[64];
  int t = threadIdx.x;
  if (t < 64){
    wq[t] = Wq ? Wq[t] : 0.0f;
    wk[t] = Wk[t];
    wv[t] = Wv[t];
  }
  __syncthreads();
  int u = blockIdx.x*256 + t;
  if (u >= nunits) return;
  const float* sp = src + (size_t)u*8;
  float xin[8];
#pragma unroll
  for (int d = 0; d < 8; ++d) xin[d] = sp[d];
#pragma unroll
  for (int d = 0; d < 8; ++d){
    float qa = 0.0f, ka = 0.0f, va = 0.0f;
#pragma unroll
    for (int d0 = 0; d0 < 8; ++d0){
      qa += xin[d0]*wq[d0*8 + d];
      ka += xin[d0]*wk[d0*8 + d];
      va += xin[d0]*wv[d0*8 + d];
    }
    if (qh) qh[(size_t)u*8 + d] = qa;
    kh[(size_t)u*8 + d] = ka;
    vh[(size_t)u*8 + d] = va;
  }
}

// =====================================================================
// fused tail: LDS-tiled register-blocked fp32 GEMMs.
// block = 256 thr = 64 rows; thread = 4 rows x 4 cols micro-tile.
// =====================================================================
__device__ __forceinline__ void gemm64x64(
    const float (* __restrict__ Xs)[68], const float* __restrict__ W,
    int Wld, int r0, int c0, float acc[4][4])
{
#pragma unroll 4
  for (int k = 0; k < 64; k += 4){
    float4 xr0 = *(const float4*)&Xs[r0+0][k];
    float4 xr1 = *(const float4*)&Xs[r0+1][k];
    float4 xr2 = *(const float4*)&Xs[r0+2][k];
    float4 xr3 = *(const float4*)&Xs[r0+3][k];
#pragma unroll
    for (int kk = 0; kk < 4; ++kk){
      float4 w = *(const float4*)&W[(size_t)(k+kk)*Wld + c0];
      float x0 = (&xr0.x)[kk], x1 = (&xr1.x)[kk];
      float x2 = (&xr2.x)[kk], x3 = (&xr3.x)[kk];
      acc[0][0] += x0*w.x; acc[0][1] += x0*w.y; acc[0][2] += x0*w.z; acc[0][3] += x0*w.w;
      acc[1][0] += x1*w.x; acc[1][1] += x1*w.y; acc[1][2] += x1*w.z; acc[1][3] += x1*w.w;
      acc[2][0] += x2*w.x; acc[2][1] += x2*w.y; acc[2][2] += x2*w.z; acc[2][3] += x2*w.w;
      acc[3][0] += x3*w.x; acc[3][1] += x3*w.y; acc[3][2] += x3*w.z; acc[3][3] += x3*w.w;
    }
  }
}

// per-row LN on the 4x4 tile (row spread across 16 lanes)
__device__ __forceinline__ void ln64(
    const float acc[4][4], float4 g, float4 b, float out[4][4])
{
#pragma unroll
  for (int i = 0; i < 4; ++i){
    float s = acc[i][0] + acc[i][1] + acc[i][2] + acc[i][3];
    float m = rowred16_sum(s) * (1.0f/64.0f);
    float d0 = acc[i][0] - m, d1 = acc[i][1] - m, d2 = acc[i][2] - m, d3 = acc[i][3] - m;
    float vv = d0*d0 + d1*d1 + d2*d2 + d3*d3;
    float var = rowred16_sum(vv) * (1.0f/64.0f);
    float rs = rsqrtf(var + 1e-5f);
    out[i][0] = d0*rs*g.x + b.x;
    out[i][1] = d1*rs*g.y + b.y;
    out[i][2] = d2*rs*g.z + b.z;
    out[i][3] = d3*rs*g.w + b.w;
  }
}

__global__ __launch_bounds__(256) void k_tail(
    const float* __restrict__ pre3, const float* __restrict__ query,
    const float* __restrict__ ds,
    const float* __restrict__ Wo, const float* __restrict__ bo,
    const float* __restrict__ g1, const float* __restrict__ be1,
    const float* __restrict__ W1, const float* __restrict__ b1,
    const float* __restrict__ W2, const float* __restrict__ b2,
    const float* __restrict__ g2, const float* __restrict__ be2,
    const float* __restrict__ Wfs, const float* __restrict__ bfs,
    float* __restrict__ outp)
{
  __shared__ float Xs[64][68];
  __shared__ float Hs[64][68];
  int tid = threadIdx.x;
  int cg = tid & 15, rg = tid >> 4;
  int r0 = rg*4, c0 = cg*4;
  int row_base = blockIdx.x * 64;            // 64 rows/block; T=128 -> n const/block
  int n = (row_base >> 7) & (Nc - 1);

  // stage pre3 tile into LDS
#pragma unroll
  for (int i = 0; i < 4; ++i){
    float4 t = *(const float4*)&pre3[(size_t)(row_base + r0 + i)*64 + c0];
    *(float4*)&Xs[r0+i][c0] = t;
  }

  float4 bo4  = *(const float4*)&bo[c0];
  float4 ds4  = *(const float4*)&ds[n*64 + c0];
  float4 g14  = *(const float4*)&g1[c0];
  float4 be14 = *(const float4*)&be1[c0];
  float4 b24  = *(const float4*)&b2[c0];
  float4 g24  = *(const float4*)&g2[c0];
  float4 be24 = *(const float4*)&be2[c0];
  float4 bfs4 = *(const float4*)&bfs[c0];
  __syncthreads();

  // ---- attn = pre3 @ Wo + bo ; v0 = attn + (query + ds) ; x = LN1(v0) ----
  float acc[4][4];
#pragma unroll
  for (int i = 0; i < 4; ++i){
    acc[i][0] = bo4.x; acc[i][1] = bo4.y; acc[i][2] = bo4.z; acc[i][3] = bo4.w;
  }
  gemm64x64(Xs, Wo, 64, r0, c0, acc);
#pragma unroll
  for (int i = 0; i < 4; ++i){
    float4 qv = *(const float4*)&query[(size_t)(row_base + r0 + i)*64 + c0];
    acc[i][0] += qv.x + ds4.x;
    acc[i][1] += qv.y + ds4.y;
    acc[i][2] += qv.z + ds4.z;
    acc[i][3] += qv.w + ds4.w;
  }
  float xt[4][4];
  ln64(acc, g14, be14, xt);
  __syncthreads();                 // all Wo-GEMM reads of Xs complete
#pragma unroll
  for (int i = 0; i < 4; ++i)
    *(float4*)&Xs[r0+i][c0] = make_float4(xt[i][0], xt[i][1], xt[i][2], xt[i][3]);
  __syncthreads();                 // Xs now holds x

  // ---- ff = relu(x @ W1 + b1) @ W2 + b2, in 4 panels of 64 hidden cols ----
  float ff[4][4];
#pragma unroll
  for (int i = 0; i < 4; ++i){
    ff[i][0] = b24.x; ff[i][1] = b24.y; ff[i][2] = b24.z; ff[i][3] = b24.w;
  }
  for (int p = 0; p < 4; ++p){
    float4 b14 = *(const float4*)&b1[p*64 + c0];
    float h[4][4];
#pragma unroll
    for (int i = 0; i < 4; ++i){
      h[i][0] = b14.x; h[i][1] = b14.y; h[i][2] = b14.z; h[i][3] = b14.w;
    }
    gemm64x64(Xs, W1 + p*64, 256, r0, c0, h);
#pragma unroll
    for (int i = 0; i < 4; ++i){
      h[i][0] = fmaxf(h[i][0], 0.0f); h[i][1] = fmaxf(h[i][1], 0.0f);
      h[i][2] = fmaxf(h[i][2], 0.0f); h[i][3] = fmaxf(h[i][3], 0.0f);
    }
    __syncthreads();               // prev panel's FF2 reads of Hs complete
#pragma unroll
    for (int i = 0; i < 4; ++i)
      *(float4*)&Hs[r0+i][c0] = make_float4(h[i][0], h[i][1], h[i][2], h[i][3]);
    __syncthreads();               // Hs holds hidden panel
    gemm64x64(Hs, W2 + (size_t)p*64*64, 64, r0, c0, ff);
  }

  // ---- u0 = ff + x ; U = LN2(u0) ----
#pragma unroll
  for (int i = 0; i < 4; ++i){
    float4 xv = *(const float4*)&Xs[r0+i][c0];
    ff[i][0] += xv.x; ff[i][1] += xv.y; ff[i][2] += xv.z; ff[i][3] += xv.w;
  }
  float U[4][4];
  ln64(ff, g24, be24, U);
  __syncthreads();                 // last FF2 reads of Hs complete
#pragma unroll
  for (int i = 0; i < 4; ++i)
    *(float4*)&Hs[r0+i][c0] = make_float4(U[i][0], U[i][1], U[i][2], U[i][3]);
  __syncthreads();                 // Hs holds U

  // ---- out = U @ Wfs + bfs ----
  float o[4][4];
#pragma unroll
  for (int i = 0; i < 4; ++i){
    o[i][0] = bfs4.x; o[i][1] = bfs4.y; o[i][2] = bfs4.z; o[i][3] = bfs4.w;
  }
  gemm64x64(Hs, Wfs, 64, r0, c0, o);
#pragma unroll
  for (int i = 0; i < 4; ++i)
    *(float4*)&outp[(size_t)(row_base + r0 + i)*64 + c0] =
        make_float4(o[i][0], o[i][1], o[i][2], o[i][3]);
}

extern "C" void kernel_launch(void* const* d_in, const int* in_sizes, int n_in,
                              void* d_out, int out_size, void* d_ws, size_t ws_size,
                              hipStream_t stream)
{
  const float* value = (const float*)d_in[0];
  const float* key   = (const float*)d_in[1];
  const float* query = (const float*)d_in[2];
  const int*  adj_sr = (const int*)d_in[3];
  const int*  adj_r  = (const int*)d_in[4];
  const float* D_S   = (const float*)d_in[5];
  const float* W_emb = (const float*)d_in[6];
  const float* b_emb = (const float*)d_in[7];
  const float* I_par = (const float*)d_in[8];
  const float* g1    = (const float*)d_in[9];
  const float* be1   = (const float*)d_in[10];
  const float* g2    = (const float*)d_in[11];
  const float* be2   = (const float*)d_in[12];
  const float* W_ff1 = (const float*)d_in[13];
  const float* b_ff1 = (const float*)d_in[14];
  const float* W_ff2 = (const float*)d_in[15];
  const float* b_ff2 = (const float*)d_in[16];
  const float* W_fs  = (const float*)d_in[17];
  const float* b_fs  = (const float*)d_in[18];
  const float* Wv_sr = (const float*)d_in[19];
  const float* Wk_sr = (const float*)d_in[20];
  const float* Wq_sr = (const float*)d_in[21];
  const float* Wo_sr = (const float*)d_in[22];
  const float* bo_sr = (const float*)d_in[23];
  const float* Wv_rr = (const float*)d_in[24];
  const float* Wk_rr = (const float*)d_in[25];
  const float* Wq_rr = (const float*)d_in[26];
  const float* Wo_rr = (const float*)d_in[27];
  const float* bo_rr = (const float*)d_in[28];
  const float* Wv_rs = (const float*)d_in[29];
  const float* Wk_rs = (const float*)d_in[30];
  const float* Wq_rs = (const float*)d_in[31];
  const float* Wo_rs = (const float*)d_in[32];
  const float* bo_rs = (const float*)d_in[33];

  float* outp  = (float*)d_out;
  float* o_out = outp;
  float* o_asr = outp + 8388608;
  float* o_arr = outp + 75497472;
  float* o_ars = outp + 83886080;
  float* o_hh  = outp + 150994944;

  // ---- workspace overlay (lifetime-checked) ----
  float* wsf = (float*)d_ws;
  float* ws_ds   = wsf;                      // 32768 floats, persistent
  float* ws_qsr  = wsf + 32768;              // 4096
  // ws_att region (33,554,432 floats): bf16 att scratch for rs stage only.
  // stage-1 PV partials alias its head (4 x 1,048,576 floats, dead before rs).
  bf16*  ws_att  = (bf16*)(wsf + 36864);
  float* ws_pre1p = wsf + 36864;             // [4][B][R][T][E] partials
  float* pool    = wsf + 36864 + 33554432;   // stage-local scratch pool
  // stage 1
  float* ws_ksr  = pool;                     // 8,388,608
  float* ws_vsr  = pool + 8388608;           // 8,388,608
  float* ws_hh1  = pool + 16777216;          // 1,048,576
  // stage 2 (ksr/vsr dead by now)
  float* ws_qrr  = pool;                     // 1,048,576
  float* ws_krr  = pool + 1048576;
  float* ws_vrr  = pool + 2097152;
  float* ws_pre2 = pool + 3145728;
  float* ws_hh2  = pool + 4194304;
  // stage 3
  float* ws_krs  = pool + 5242880;
  float* ws_vrs  = pool + 6291456;
  float* ws_pre3 = pool + 7340032;           // 8,388,608

  // ---- stage 1: sr attention (direct fp32 asr write) ----
  k_prep<<<576, 64, 0, stream>>>(D_S, W_emb, b_emb, I_par, Wq_sr, ws_ds, ws_qsr);
  k_proj_sr<<<4096, 256, 0, stream>>>(key, value, ws_ds, Wk_sr, Wv_sr, ws_ksr, ws_vsr);
  k_attn_sr<<<1024, 256, 0, stream>>>(ws_ksr, ws_vsr, ws_qsr, adj_sr, o_asr, ws_pre1p);
  k_wo<<<4096, 256, 0, stream>>>(ws_pre1p, 4, 1048576, Wo_sr, bo_sr,
                                 ws_hh1, (float*)nullptr, 16384);

  // ---- stage 2: rr attention (direct fp32 arr write) ----
  k_proj3<<<512, 256, 0, stream>>>(ws_hh1, Wq_rr, Wk_rr, Wv_rr,
                                   ws_qrr, ws_krr, ws_vrr, 131072);
  k_attn_rr<<<256, 256, 0, stream>>>(ws_qrr, ws_krr, ws_vrr, adj_r, o_arr, ws_pre2);
  k_wo<<<4096, 256, 0, stream>>>(ws_pre2, 1, 0, Wo_rr, bo_rr, ws_hh2, o_hh, 16384);

  // ---- stage 3: rs attention ----
  k_proj3<<<512, 256, 0, stream>>>(ws_hh2, (const float*)nullptr, Wk_rs, Wv_rs,
                                   (float*)nullptr, ws_krs, ws_vrs, 131072);
  k_attn_rs<<<2048, 512, 0, stream>>>(query, ws_ds, Wq_rs, ws_krs, ws_vrs,
                                      ws_att, ws_pre3);
  k_transpose<<<16384, 256, 0, stream>>>((const unsigned short*)ws_att, o_ars, 64, 512);

  // ---- tail: Wo_rs + LN + FF + LN + W_fs (fused, LDS-tiled fp32 GEMM) ----
  k_tail<<<2048, 256, 0, stream>>>(ws_pre3, query, ws_ds, Wo_rs, bo_rs,
                                   g1, be1, W_ff1, b_ff1, W_ff2, b_ff2,
                                   g2, be2, W_fs, b_fs, o_out);
}

// Round 4
// 848.222 us; speedup vs baseline: 1.1684x; 1.1684x over previous
//
#include <hip/hip_runtime.h>
#include <hip/hip_bf16.h>

typedef __hip_bfloat16 bf16;

#define Bc 2
#define Nc 512
#define Rc 64
#define Tc 128
#define Ec 64
#define Hc 8
#define THc 1024
#define FFc 256

__device__ __forceinline__ bf16  f2b(float x){ return __float2bfloat16(x); }
__device__ __forceinline__ float us2f(unsigned short u){
  union { unsigned int i; float f; } c; c.i = ((unsigned int)u) << 16; return c.f;
}
__device__ __forceinline__ float clip5(float x){ return fminf(fmaxf(x, -5.0f), 5.0f); }

__device__ __forceinline__ float wave_sum64(float v){
#pragma unroll
  for (int o = 32; o > 0; o >>= 1) v += __shfl_xor(v, o, 64);
  return v;
}
// two interleaved wave sums (ILP across the serial shuffle chain)
__device__ __forceinline__ void wave_sum64x2(float& a, float& b){
#pragma unroll
  for (int o = 32; o > 0; o >>= 1){
    a += __shfl_xor(a, o, 64);
    b += __shfl_xor(b, o, 64);
  }
}

// sum across the 16 lanes that co-own one row (lanes are 16-aligned groups)
__device__ __forceinline__ float rowred16_sum(float v){
  v += __shfl_xor(v, 1, 64);
  v += __shfl_xor(v, 2, 64);
  v += __shfl_xor(v, 4, 64);
  v += __shfl_xor(v, 8, 64);
  return v;
}

// ---------------- prep: ds = D_S@W_emb + b_emb ; qhat_sr = I_param(head)@Wq_sr ----
__global__ __launch_bounds__(64) void k_prep(
    const float* __restrict__ DS, const float* __restrict__ Wemb,
    const float* __restrict__ bemb, const float* __restrict__ Ip,
    const float* __restrict__ Wq, float* __restrict__ ds, float* __restrict__ qhat)
{
  int bid = blockIdx.x, t = threadIdx.x;
  if (bid < Nc){
    int n = bid, e = t;
    __shared__ float row[Rc];
    row[t] = DS[n*Rc + t];
    __syncthreads();
    float acc = bemb[e];
    for (int r = 0; r < Rc; ++r) acc += row[r] * Wemb[r*Ec + e];
    ds[n*Ec + e] = acc;
  } else {
    int r = bid - Nc;
    __shared__ float irow[Ec];
    irow[t] = Ip[r*Ec + t];
    __syncthreads();
    int h = t >> 3, d = t & 7;
    float acc = 0.0f;
#pragma unroll
    for (int d0 = 0; d0 < 8; ++d0) acc += irow[h*8 + d0] * Wq[d0*8 + d];
    qhat[r*Ec + h*8 + d] = acc;   // [R][H][D]
  }
}

// ---------------- khat_sr = (key+ds)@Wk per head; vhat_sr = value@Wv --------------
__global__ __launch_bounds__(256) void k_proj_sr(
    const float* __restrict__ key, const float* __restrict__ value,
    const float* __restrict__ ds, const float* __restrict__ Wk,
    const float* __restrict__ Wv, float* __restrict__ khat, float* __restrict__ vhat)
{
  __shared__ float wk[64], wv[64];
  int t = threadIdx.x;
  if (t < 64){ wk[t] = Wk[t]; wv[t] = Wv[t]; }
  __syncthreads();
  int u = blockIdx.x*256 + t;              // (b,n,t,h) unit, < 1048576
  int h = u & 7;
  int nt = u >> 3;                         // (b*N+n)*T + t
  int n = (nt / Tc) % Nc;
  const float* kp = key + (size_t)u*8;
  const float* vp = value + (size_t)u*8;
  const float* dsp = ds + n*Ec + h*8;
  float kin[8], vin[8];
#pragma unroll
  for (int d = 0; d < 8; ++d){ kin[d] = kp[d] + dsp[d]; vin[d] = vp[d]; }
  float* ko = khat + (size_t)u*8;
  float* vo = vhat + (size_t)u*8;
#pragma unroll
  for (int d = 0; d < 8; ++d){
    float ka = 0.0f, va = 0.0f;
#pragma unroll
    for (int d0 = 0; d0 < 8; ++d0){ ka += kin[d0]*wk[d0*8+d]; va += vin[d0]*wv[d0*8+d]; }
    ko[d] = ka; vo[d] = va;
  }
}

// ---------------- sr attention (PV only): block=(b,t,h) x 4 waves ---------------
// softmax over r (= lane); n-loop split across 4 waves, PV partials LDS-reduced.
// e clipped to [-5,5] -> exp() safe without max subtraction. No att write here.
__global__ __launch_bounds__(256) void k_attn_sr(
    const float* __restrict__ khat, const float* __restrict__ vhat,
    const float* __restrict__ qhat, const int* __restrict__ adj_sr,
    float* __restrict__ pre)
{
  __shared__ float accs[4][64][8];
  int bid = blockIdx.x;
  int b = bid >> 10, th = bid & 1023;
  int t = th >> 3, h = th & 7;
  int tid = threadIdx.x;
  int r = tid & 63, w = tid >> 6;
  float q[8];
#pragma unroll
  for (int d = 0; d < 8; ++d) q[d] = qhat[r*Ec + h*8 + d];
  float acc[8] = {0,0,0,0,0,0,0,0};
  int n0 = w*128;
  for (int n = n0; n < n0 + 128; n += 2){
    size_t goA = ((size_t)((b*Nc + n)*Tc + t))*Ec + h*8;
    size_t goB = goA + (size_t)Tc*Ec;
    const float* kA = khat + goA;
    const float* kB = khat + goB;
    float eA = 0.0f, eB = 0.0f;
#pragma unroll
    for (int d = 0; d < 8; ++d){ eA += q[d]*kA[d]; eB += q[d]*kB[d]; }
    int mA = adj_sr[n*Rc + r], mB = adj_sr[(n+1)*Rc + r];
    eA = mA ? clip5(eA*0.125f) : -5.0f;
    eB = mB ? clip5(eB*0.125f) : -5.0f;
    float pA = __expf(eA), pB = __expf(eB);
    float sA = pA, sB = pB;
    wave_sum64x2(sA, sB);
    float aA = pA/sA, aB = pB/sB;
    const float* vA = vhat + goA;
    const float* vB = vhat + goB;
#pragma unroll
    for (int d = 0; d < 8; ++d) acc[d] += aA*vA[d] + aB*vB[d];
  }
#pragma unroll
  for (int d = 0; d < 8; ++d) accs[w][r][d] = acc[d];
  __syncthreads();
  if (w == 0){
    size_t po = ((size_t)((b*Rc + r)*Tc + t))*Ec + h*8;   // [B][R][T][E]
#pragma unroll
    for (int d = 0; d < 8; ++d)
      pre[po + d] = accs[0][r][d] + accs[1][r][d] + accs[2][r][d] + accs[3][r][d];
  }
}

// ---------------- asr writer: lane = t -> fully coalesced fp32 asr --------------
// block = (b, n-pair), 256 thr: n = n0 + (tid>>7), t = tid&127.
// Softmax denominator over r is in-thread (no shuffles). Two passes over r
// (denominator, then normalize+store). Mask is wave-uniform -> masked r skips
// the dot/exp. Writes: per r, lanes t=0..63 store contiguous 2KB (full lines).
__global__ __launch_bounds__(256) void k_asr_write(
    const float* __restrict__ khat, const float* __restrict__ qhat,
    const int* __restrict__ adj_sr, float* __restrict__ o_asr)
{
  __shared__ float ql[4096];                 // q [r][h*8+d]
  const float EXPM5 = 0.006737946999085467f; // exp(-5)
  int bid = blockIdx.x;                      // b*256 + npair
  int b = bid >> 8, np = bid & 255;
  int tid = threadIdx.x;
  int n = np*2 + (tid >> 7);
  int t = tid & 127;
#pragma unroll
  for (int i = 0; i < 16; ++i) ql[i*256 + tid] = qhat[i*256 + tid];
  __syncthreads();
  const float* kp = khat + ((size_t)((b*Nc + n)*Tc + t))*Ec;
  float kr[64];
#pragma unroll
  for (int i = 0; i < 16; ++i) *(float4*)&kr[i*4] = *(const float4*)&kp[i*4];

  // pass 1: denominators s[h] = sum_r exp(e[r][h])
  float s[8] = {0,0,0,0,0,0,0,0};
  for (int r = 0; r < 64; ++r){
    int m = adj_sr[n*Rc + r];                // wave-uniform
    if (m){
      const float* qr = &ql[r*64];
#pragma unroll
      for (int h = 0; h < 8; ++h){
        float4 qa = *(const float4*)&qr[h*8];
        float4 qb = *(const float4*)&qr[h*8 + 4];
        float e = qa.x*kr[h*8+0] + qa.y*kr[h*8+1] + qa.z*kr[h*8+2] + qa.w*kr[h*8+3]
                + qb.x*kr[h*8+4] + qb.y*kr[h*8+5] + qb.z*kr[h*8+6] + qb.w*kr[h*8+7];
        s[h] += __expf(clip5(e*0.125f));
      }
    } else {
#pragma unroll
      for (int h = 0; h < 8; ++h) s[h] += EXPM5;
    }
  }
  float rs_[8];
#pragma unroll
  for (int h = 0; h < 8; ++h) rs_[h] = __builtin_amdgcn_rcpf(s[h]);

  // pass 2: normalize + coalesced store
  for (int r = 0; r < 64; ++r){
    int m = adj_sr[n*Rc + r];
    float a[8];
    if (m){
      const float* qr = &ql[r*64];
#pragma unroll
      for (int h = 0; h < 8; ++h){
        float4 qa = *(const float4*)&qr[h*8];
        float4 qb = *(const float4*)&qr[h*8 + 4];
        float e = qa.x*kr[h*8+0] + qa.y*kr[h*8+1] + qa.z*kr[h*8+2] + qa.w*kr[h*8+3]
                + qb.x*kr[h*8+4] + qb.y*kr[h*8+5] + qb.z*kr[h*8+6] + qb.w*kr[h*8+7];
        a[h] = __expf(clip5(e*0.125f)) * rs_[h];
      }
    } else {
#pragma unroll
      for (int h = 0; h < 8; ++h) a[h] = EXPM5 * rs_[h];
    }
    size_t ao = ((size_t)((b*Rc + r)*Nc + n))*THc + t*8;  // [B][R][N][T*8+h]
    *(float4*)&o_asr[ao]     = make_float4(a[0], a[1], a[2], a[3]);
    *(float4*)&o_asr[ao + 4] = make_float4(a[4], a[5], a[6], a[7]);
  }
}

// ---------------- rr attention: block=(b,t,h) x 4 waves; wave=k-chunk -----------
__global__ __launch_bounds__(256) void k_attn_rr(
    const float* __restrict__ qh, const float* __restrict__ kh,
    const float* __restrict__ vh, const int* __restrict__ adj_r,
    bf16* __restrict__ att_c, float* __restrict__ pre)
{
  __shared__ float accs[4][64][8];
  int bid = blockIdx.x;
  int b = bid >> 10, th = bid & 1023;
  int t = th >> 3, h = th & 7;
  int tid = threadIdx.x;
  int q = tid & 63, w = tid >> 6;
  size_t qo = ((size_t)((b*Rc + q)*Tc + t))*Ec + h*8;
  float qv[8];
#pragma unroll
  for (int d = 0; d < 8; ++d) qv[d] = qh[qo + d];
  float acc[8] = {0,0,0,0,0,0,0,0};
  int k0 = w*16;
  for (int k = k0; k < k0 + 16; k += 2){
    size_t koA = ((size_t)((b*Rc + k)*Tc + t))*Ec + h*8;
    size_t koB = koA + (size_t)Tc*Ec;
    const float* kA = kh + koA;
    const float* kB = kh + koB;
    float eA = 0.0f, eB = 0.0f;
#pragma unroll
    for (int d = 0; d < 8; ++d){ eA += qv[d]*kA[d]; eB += qv[d]*kB[d]; }
    int mA = adj_r[q*Rc + k], mB = adj_r[q*Rc + k + 1];
    eA = mA ? clip5(eA*0.125f) : -5.0f;
    eB = mB ? clip5(eB*0.125f) : -5.0f;
    float pA = __expf(eA), pB = __expf(eB);
    float sA = pA, sB = pB;
    wave_sum64x2(sA, sB);
    float aA = pA/sA, aB = pB/sB;
    size_t ao = ((size_t)(b*Rc + k)*THc + th)*Rc + q;
    att_c[ao] = f2b(aA);                              // [B][K][TH][Q=64]
    att_c[ao + (size_t)THc*Rc] = f2b(aB);
    const float* vA = vh + koA;
    const float* vB = vh + koB;
#pragma unroll
    for (int d = 0; d < 8; ++d) acc[d] += aA*vA[d] + aB*vB[d];
  }
#pragma unroll
  for (int d = 0; d < 8; ++d) accs[w][q][d] = acc[d];
  __syncthreads();
  if (w == 0){
#pragma unroll
    for (int d = 0; d < 8; ++d)
      pre[qo + d] = accs[0][q][d] + accs[1][q][d] + accs[2][q][d] + accs[3][q][d];
  }
}

// ---------------- rs attention: block=(b,t,h) x 512 thr, thread=q ---------------
__global__ __launch_bounds__(512) void k_attn_rs(
    const float* __restrict__ query, const float* __restrict__ ds,
    const float* __restrict__ Wq, const float* __restrict__ kh,
    const float* __restrict__ vh, bf16* __restrict__ att_c, float* __restrict__ pre)
{
  __shared__ float wq[64];
  __shared__ float kl[64][8];
  __shared__ float vl[64][8];
  __shared__ float redS[2][2][8];
  int bid = blockIdx.x;
  int b = bid >> 10, th = bid & 1023;
  int t = th >> 3, h = th & 7;
  int q = threadIdx.x;
  if (q < 64) wq[q] = Wq[q];
  {
    int kk = q >> 3, d = q & 7;
    size_t o = ((size_t)((b*Rc + kk)*Tc + t))*Ec + h*8 + d;
    kl[kk][d] = kh[o];
    vl[kk][d] = vh[o];
  }
  __syncthreads();
  size_t qro = ((size_t)((b*Nc + q)*Tc + t))*Ec + h*8;
  const float* dsp = ds + q*Ec + h*8;
  float xin[8], qv[8];
#pragma unroll
  for (int d = 0; d < 8; ++d) xin[d] = query[qro + d] + dsp[d];
#pragma unroll
  for (int d = 0; d < 8; ++d){
    float a = 0.0f;
#pragma unroll
    for (int d0 = 0; d0 < 8; ++d0) a += xin[d0]*wq[d0*8 + d];
    qv[d] = a;
  }
  float acc[8] = {0,0,0,0,0,0,0,0};
  int lane = q & 63, wv = q >> 6;
  for (int k = 0; k < 64; k += 2){
    float eA = 0.0f, eB = 0.0f;
#pragma unroll
    for (int d = 0; d < 8; ++d){ eA += qv[d]*kl[k][d]; eB += qv[d]*kl[k+1][d]; }
    eA = clip5(eA*0.125f);
    eB = clip5(eB*0.125f);
    float pA = __expf(eA), pB = __expf(eB);
    float sA = pA, sB = pB;
    wave_sum64x2(sA, sB);
    int pb = (k >> 1) & 1;
    if (lane == 0){ redS[pb][0][wv] = sA; redS[pb][1][wv] = sB; }
    __syncthreads();
    float stA = 0.0f, stB = 0.0f;
#pragma unroll
    for (int i = 0; i < 8; ++i){ stA += redS[pb][0][i]; stB += redS[pb][1][i]; }
    float aA = pA/stA, aB = pB/stB;
    size_t ao = ((size_t)(b*Rc + k)*THc + th)*Nc + q;
    att_c[ao] = f2b(aA);                              // [B][K][TH][Q=512]
    att_c[ao + (size_t)THc*Nc] = f2b(aB);
#pragma unroll
    for (int d = 0; d < 8; ++d) acc[d] += aA*vl[k][d] + aB*vl[k+1][d];
  }
#pragma unroll
  for (int d = 0; d < 8; ++d) pre[qro + d] = acc[d];         // [B][N][T][E]
}

// ---- transpose+widen: src bf16 [B][W][TH][C] -> dst fp32 [((b*C+c)*W+w)*TH+th] --
__global__ __launch_bounds__(256) void k_transpose(
    const unsigned short* __restrict__ src, float* __restrict__ dst,
    int W, int C)
{
  __shared__ unsigned short tile[64][66];
  int bid = blockIdx.x;
  int nct = C >> 6;
  int ct = bid % nct; bid /= nct;
  int tht = bid & 15; bid >>= 4;
  int w = bid % W; int b = bid / W;
  int tt = threadIdx.x;
  {
    int cs = tt & 63, i0 = tt >> 6;
    const unsigned short* sb = src + ((size_t)(b*W + w)*THc + tht*64)*C + ct*64;
#pragma unroll
    for (int p = 0; p < 16; ++p){
      int i = i0 + p*4;
      tile[i][cs] = sb[(size_t)i*C + cs];
    }
  }
  __syncthreads();
  {
    int i = tt & 63, c0 = tt >> 6;
#pragma unroll
    for (int p = 0; p < 16; ++p){
      int cs = c0 + p*4;
      int c = ct*64 + cs;
      dst[((size_t)(b*C + c)*W + w)*THc + tht*64 + i] = us2f(tile[i][cs]);
    }
  }
}

// -------- Wo projection: wave per row, (sum of nparts partials) @ Wo + bo -------
__global__ __launch_bounds__(256) void k_wo(
    const float* __restrict__ pre, int nparts, int pstride,
    const float* __restrict__ Wo,
    const float* __restrict__ bo, float* __restrict__ outf,
    float* __restrict__ outf2, int nrows)
{
  int gt = blockIdx.x*256 + threadIdx.x;
  int row = gt >> 6, lane = gt & 63;
  if (row >= nrows) return;
  float xin = 0.0f;
  for (int p2 = 0; p2 < nparts; ++p2)
    xin += pre[(size_t)p2*pstride + (size_t)row*64 + lane];
  float acc = bo[lane];
  for (int e = 0; e < 64; ++e){
    float xe = __shfl(xin, e, 64);
    acc += xe * Wo[e*64 + lane];
  }
  outf[(size_t)row*64 + lane] = acc;
  if (outf2) outf2[(size_t)row*64 + lane] = acc;
}

// ---------------- per-head triple projection from [rows][64] fp32 ---------------
__global__ __launch_bounds__(256) void k_proj3(
    const float* __restrict__ src, const float* Wq, const float* Wk, const float* Wv,
    float* qh, float* kh, float* vh, int nunits)
{
  __shared__ float wq[64], wk[64], wv[64];
  int t = threadIdx.x;
  if (t < 64){
    wq[t] = Wq ? Wq[t] : 0.0f;
    wk[t] = Wk[t];
    wv[t] = Wv[t];
  }
  __syncthreads();
  int u = blockIdx.x*256 + t;
  if (u >= nunits) return;
  const float* sp = src + (size_t)u*8;
  float xin[8];
#pragma unroll
  for (int d = 0; d < 8; ++d) xin[d] = sp[d];
#pragma unroll
  for (int d = 0; d < 8; ++d){
    float qa = 0.0f, ka = 0.0f, va = 0.0f;
#pragma unroll
    for (int d0 = 0; d0 < 8; ++d0){
      qa += xin[d0]*wq[d0*8 + d];
      ka += xin[d0]*wk[d0*8 + d];
      va += xin[d0]*wv[d0*8 + d];
    }
    if (qh) qh[(size_t)u*8 + d] = qa;
    kh[(size_t)u*8 + d] = ka;
    vh[(size_t)u*8 + d] = va;
  }
}

// =====================================================================
// fused tail: LDS-tiled register-blocked fp32 GEMMs.
// block = 256 thr = 64 rows; thread = 4 rows x 4 cols micro-tile.
// =====================================================================
__device__ __forceinline__ void gemm64x64(
    const float (* __restrict__ Xs)[68], const float* __restrict__ W,
    int Wld, int r0, int c0, float acc[4][4])
{
#pragma unroll 4
  for (int k = 0; k < 64; k += 4){
    float4 xr0 = *(const float4*)&Xs[r0+0][k];
    float4 xr1 = *(const float4*)&Xs[r0+1][k];
    float4 xr2 = *(const float4*)&Xs[r0+2][k];
    float4 xr3 = *(const float4*)&Xs[r0+3][k];
#pragma unroll
    for (int kk = 0; kk < 4; ++kk){
      float4 w = *(const float4*)&W[(size_t)(k+kk)*Wld + c0];
      float x0 = (&xr0.x)[kk], x1 = (&xr1.x)[kk];
      float x2 = (&xr2.x)[kk], x3 = (&xr3.x)[kk];
      acc[0][0] += x0*w.x; acc[0][1] += x0*w.y; acc[0][2] += x0*w.z; acc[0][3] += x0*w.w;
      acc[1][0] += x1*w.x; acc[1][1] += x1*w.y; acc[1][2] += x1*w.z; acc[1][3] += x1*w.w;
      acc[2][0] += x2*w.x; acc[2][1] += x2*w.y; acc[2][2] += x2*w.z; acc[2][3] += x2*w.w;
      acc[3][0] += x3*w.x; acc[3][1] += x3*w.y; acc[3][2] += x3*w.z; acc[3][3] += x3*w.w;
    }
  }
}

// per-row LN on the 4x4 tile (row spread across 16 lanes)
__device__ __forceinline__ void ln64(
    const float acc[4][4], float4 g, float4 b, float out[4][4])
{
#pragma unroll
  for (int i = 0; i < 4; ++i){
    float s = acc[i][0] + acc[i][1] + acc[i][2] + acc[i][3];
    float m = rowred16_sum(s) * (1.0f/64.0f);
    float d0 = acc[i][0] - m, d1 = acc[i][1] - m, d2 = acc[i][2] - m, d3 = acc[i][3] - m;
    float vv = d0*d0 + d1*d1 + d2*d2 + d3*d3;
    float var = rowred16_sum(vv) * (1.0f/64.0f);
    float rs = rsqrtf(var + 1e-5f);
    out[i][0] = d0*rs*g.x + b.x;
    out[i][1] = d1*rs*g.y + b.y;
    out[i][2] = d2*rs*g.z + b.z;
    out[i][3] = d3*rs*g.w + b.w;
  }
}

__global__ __launch_bounds__(256) void k_tail(
    const float* __restrict__ pre3, const float* __restrict__ query,
    const float* __restrict__ ds,
    const float* __restrict__ Wo, const float* __restrict__ bo,
    const float* __restrict__ g1, const float* __restrict__ be1,
    const float* __restrict__ W1, const float* __restrict__ b1,
    const float* __restrict__ W2, const float* __restrict__ b2,
    const float* __restrict__ g2, const float* __restrict__ be2,
    const float* __restrict__ Wfs, const float* __restrict__ bfs,
    float* __restrict__ outp)
{
  __shared__ float Xs[64][68];
  __shared__ float Hs[64][68];
  int tid = threadIdx.x;
  int cg = tid & 15, rg = tid >> 4;
  int r0 = rg*4, c0 = cg*4;
  int row_base = blockIdx.x * 64;            // 64 rows/block; T=128 -> n const/block
  int n = (row_base >> 7) & (Nc - 1);

  // stage pre3 tile into LDS
#pragma unroll
  for (int i = 0; i < 4; ++i){
    float4 t = *(const float4*)&pre3[(size_t)(row_base + r0 + i)*64 + c0];
    *(float4*)&Xs[r0+i][c0] = t;
  }

  float4 bo4  = *(const float4*)&bo[c0];
  float4 ds4  = *(const float4*)&ds[n*64 + c0];
  float4 g14  = *(const float4*)&g1[c0];
  float4 be14 = *(const float4*)&be1[c0];
  float4 b24  = *(const float4*)&b2[c0];
  float4 g24  = *(const float4*)&g2[c0];
  float4 be24 = *(const float4*)&be2[c0];
  float4 bfs4 = *(const float4*)&bfs[c0];
  __syncthreads();

  // ---- attn = pre3 @ Wo + bo ; v0 = attn + (query + ds) ; x = LN1(v0) ----
  float acc[4][4];
#pragma unroll
  for (int i = 0; i < 4; ++i){
    acc[i][0] = bo4.x; acc[i][1] = bo4.y; acc[i][2] = bo4.z; acc[i][3] = bo4.w;
  }
  gemm64x64(Xs, Wo, 64, r0, c0, acc);
#pragma unroll
  for (int i = 0; i < 4; ++i){
    float4 qv = *(const float4*)&query[(size_t)(row_base + r0 + i)*64 + c0];
    acc[i][0] += qv.x + ds4.x;
    acc[i][1] += qv.y + ds4.y;
    acc[i][2] += qv.z + ds4.z;
    acc[i][3] += qv.w + ds4.w;
  }
  float xt[4][4];
  ln64(acc, g14, be14, xt);
  __syncthreads();                 // all Wo-GEMM reads of Xs complete
#pragma unroll
  for (int i = 0; i < 4; ++i)
    *(float4*)&Xs[r0+i][c0] = make_float4(xt[i][0], xt[i][1], xt[i][2], xt[i][3]);
  __syncthreads();                 // Xs now holds x

  // ---- ff = relu(x @ W1 + b1) @ W2 + b2, in 4 panels of 64 hidden cols ----
  float ff[4][4];
#pragma unroll
  for (int i = 0; i < 4; ++i){
    ff[i][0] = b24.x; ff[i][1] = b24.y; ff[i][2] = b24.z; ff[i][3] = b24.w;
  }
  for (int p = 0; p < 4; ++p){
    float4 b14 = *(const float4*)&b1[p*64 + c0];
    float h[4][4];
#pragma unroll
    for (int i = 0; i < 4; ++i){
      h[i][0] = b14.x; h[i][1] = b14.y; h[i][2] = b14.z; h[i][3] = b14.w;
    }
    gemm64x64(Xs, W1 + p*64, 256, r0, c0, h);
#pragma unroll
    for (int i = 0; i < 4; ++i){
      h[i][0] = fmaxf(h[i][0], 0.0f); h[i][1] = fmaxf(h[i][1], 0.0f);
      h[i][2] = fmaxf(h[i][2], 0.0f); h[i][3] = fmaxf(h[i][3], 0.0f);
    }
    __syncthreads();               // prev panel's FF2 reads of Hs complete
#pragma unroll
    for (int i = 0; i < 4; ++i)
      *(float4*)&Hs[r0+i][c0] = make_float4(h[i][0], h[i][1], h[i][2], h[i][3]);
    __syncthreads();               // Hs holds hidden panel
    gemm64x64(Hs, W2 + (size_t)p*64*64, 64, r0, c0, ff);
  }

  // ---- u0 = ff + x ; U = LN2(u0) ----
#pragma unroll
  for (int i = 0; i < 4; ++i){
    float4 xv = *(const float4*)&Xs[r0+i][c0];
    ff[i][0] += xv.x; ff[i][1] += xv.y; ff[i][2] += xv.z; ff[i][3] += xv.w;
  }
  float U[4][4];
  ln64(ff, g24, be24, U);
  __syncthreads();                 // last FF2 reads of Hs complete
#pragma unroll
  for (int i = 0; i < 4; ++i)
    *(float4*)&Hs[r0+i][c0] = make_float4(U[i][0], U[i][1], U[i][2], U[i][3]);
  __syncthreads();                 // Hs holds U

  // ---- out = U @ Wfs + bfs ----
  float o[4][4];
#pragma unroll
  for (int i = 0; i < 4; ++i){
    o[i][0] = bfs4.x; o[i][1] = bfs4.y; o[i][2] = bfs4.z; o[i][3] = bfs4.w;
  }
  gemm64x64(Hs, Wfs, 64, r0, c0, o);
#pragma unroll
  for (int i = 0; i < 4; ++i)
    *(float4*)&outp[(size_t)(row_base + r0 + i)*64 + c0] =
        make_float4(o[i][0], o[i][1], o[i][2], o[i][3]);
}

extern "C" void kernel_launch(void* const* d_in, const int* in_sizes, int n_in,
                              void* d_out, int out_size, void* d_ws, size_t ws_size,
                              hipStream_t stream)
{
  const float* value = (const float*)d_in[0];
  const float* key   = (const float*)d_in[1];
  const float* query = (const float*)d_in[2];
  const int*  adj_sr = (const int*)d_in[3];
  const int*  adj_r  = (const int*)d_in[4];
  const float* D_S   = (const float*)d_in[5];
  const float* W_emb = (const float*)d_in[6];
  const float* b_emb = (const float*)d_in[7];
  const float* I_par = (const float*)d_in[8];
  const float* g1    = (const float*)d_in[9];
  const float* be1   = (const float*)d_in[10];
  const float* g2    = (const float*)d_in[11];
  const float* be2   = (const float*)d_in[12];
  const float* W_ff1 = (const float*)d_in[13];
  const float* b_ff1 = (const float*)d_in[14];
  const float* W_ff2 = (const float*)d_in[15];
  const float* b_ff2 = (const float*)d_in[16];
  const float* W_fs  = (const float*)d_in[17];
  const float* b_fs  = (const float*)d_in[18];
  const float* Wv_sr = (const float*)d_in[19];
  const float* Wk_sr = (const float*)d_in[20];
  const float* Wq_sr = (const float*)d_in[21];
  const float* Wo_sr = (const float*)d_in[22];
  const float* bo_sr = (const float*)d_in[23];
  const float* Wv_rr = (const float*)d_in[24];
  const float* Wk_rr = (const float*)d_in[25];
  const float* Wq_rr = (const float*)d_in[26];
  const float* Wo_rr = (const float*)d_in[27];
  const float* bo_rr = (const float*)d_in[28];
  const float* Wv_rs = (const float*)d_in[29];
  const float* Wk_rs = (const float*)d_in[30];
  const float* Wq_rs = (const float*)d_in[31];
  const float* Wo_rs = (const float*)d_in[32];
  const float* bo_rs = (const float*)d_in[33];

  float* outp  = (float*)d_out;
  float* o_out = outp;
  float* o_asr = outp + 8388608;
  float* o_arr = outp + 75497472;
  float* o_ars = outp + 83886080;
  float* o_hh  = outp + 150994944;

  // ---- workspace overlay (lifetime-checked) ----
  float* wsf = (float*)d_ws;
  float* ws_ds   = wsf;                      // 32768 floats, persistent
  float* ws_qsr  = wsf + 32768;              // 4096
  bf16*  ws_att  = (bf16*)(wsf + 36864);     // bf16 att scratch (rr + rs stages)
  float* pool    = wsf + 36864 + 33554432;   // stage-local scratch pool
  // stage 1
  float* ws_ksr  = pool;                     // 8,388,608
  float* ws_vsr  = pool + 8388608;           // 8,388,608
  float* ws_pre1 = pool + 16777216;          // 1,048,576
  float* ws_hh1  = pool + 17825792;          // 1,048,576
  // stage 2 (ksr/vsr dead by now)
  float* ws_qrr  = pool;                     // 1,048,576
  float* ws_krr  = pool + 1048576;
  float* ws_vrr  = pool + 2097152;
  float* ws_pre2 = pool + 3145728;
  float* ws_hh2  = pool + 4194304;
  // stage 3
  float* ws_krs  = pool + 5242880;
  float* ws_vrs  = pool + 6291456;
  float* ws_pre3 = pool + 7340032;           // 8,388,608

  // ---- stage 1: sr attention (PV kernel + coalesced asr writer) ----
  k_prep<<<576, 64, 0, stream>>>(D_S, W_emb, b_emb, I_par, Wq_sr, ws_ds, ws_qsr);
  k_proj_sr<<<4096, 256, 0, stream>>>(key, value, ws_ds, Wk_sr, Wv_sr, ws_ksr, ws_vsr);
  k_attn_sr<<<2048, 256, 0, stream>>>(ws_ksr, ws_vsr, ws_qsr, adj_sr, ws_pre1);
  k_asr_write<<<512, 256, 0, stream>>>(ws_ksr, ws_qsr, adj_sr, o_asr);
  k_wo<<<4096, 256, 0, stream>>>(ws_pre1, 1, 0, Wo_sr, bo_sr,
                                 ws_hh1, (float*)nullptr, 16384);

  // ---- stage 2: rr attention ----
  k_proj3<<<512, 256, 0, stream>>>(ws_hh1, Wq_rr, Wk_rr, Wv_rr,
                                   ws_qrr, ws_krr, ws_vrr, 131072);
  k_attn_rr<<<2048, 256, 0, stream>>>(ws_qrr, ws_krr, ws_vrr, adj_r, ws_att, ws_pre2);
  k_transpose<<<2048, 256, 0, stream>>>((const unsigned short*)ws_att, o_arr, 64, 64);
  k_wo<<<4096, 256, 0, stream>>>(ws_pre2, 1, 0, Wo_rr, bo_rr, ws_hh2, o_hh, 16384);

  // ---- stage 3: rs attention ----
  k_proj3<<<512, 256, 0, stream>>>(ws_hh2, (const float*)nullptr, Wk_rs, Wv_rs,
                                   (float*)nullptr, ws_krs, ws_vrs, 131072);
  k_attn_rs<<<2048, 512, 0, stream>>>(query, ws_ds, Wq_rs, ws_krs, ws_vrs,
                                      ws_att, ws_pre3);
  k_transpose<<<16384, 256, 0, stream>>>((const unsigned short*)ws_att, o_ars, 64, 512);

  // ---- tail: Wo_rs + LN + FF + LN + W_fs (fused, LDS-tiled fp32 GEMM) ----
  k_tail<<<2048, 256, 0, stream>>>(ws_pre3, query, ws_ds, Wo_rs, bo_rs,
                                   g1, be1, W_ff1, b_ff1, W_ff2, b_ff2,
                                   g2, be2, W_fs, b_fs, o_out);
}